// Round 5
// baseline (534.581 us; speedup 1.0000x reference)
//
#include <hip/hip_runtime.h>
#include <math.h>

#define N_NODES 50000
#define N_EDGES 800000
#define HD 128          // H*D = 4*32
#define GG 1024
#define NEG_SLOPE 0.2f
#define SCAN_B 1024
#define NB ((N_NODES + SCAN_B - 1) / SCAN_B)   // 49

typedef __attribute__((ext_vector_type(8))) short bf16x8;
typedef __attribute__((ext_vector_type(4))) float f32x4;

__device__ __forceinline__ unsigned short f2bf(float v) {
    unsigned u = __float_as_uint(v);
    u += 0x7fff + ((u >> 16) & 1);       // round-to-nearest-even
    return (unsigned short)(u >> 16);
}
__device__ __forceinline__ float bf2f(unsigned short s) {
    return __uint_as_float((unsigned)s << 16);
}

// --------------------------------------------------- split-bf16 conversions
__global__ void convert_x(const float* __restrict__ x, unsigned short* __restrict__ Xh,
                          unsigned short* __restrict__ Xl, int total)
{
    int i = blockIdx.x * 256 + threadIdx.x;
    if (i >= total) return;
    float v = x[i];
    unsigned short hi = f2bf(v);
    unsigned short lo = f2bf(v - bf2f(hi));   // residual exact in fp32
    Xh[i] = hi; Xl[i] = lo;
}

// W (K x 128) pair -> Wt (256 x K) transposed, split hi/lo. rows 0..127 = Wl cols.
__global__ void convert_w(const float* __restrict__ Wl, const float* __restrict__ Wr,
                          unsigned short* __restrict__ Wth, unsigned short* __restrict__ Wtl,
                          int K)
{
    int t = blockIdx.x * 256 + threadIdx.x;
    if (t >= 256 * K) return;
    int c = t / K, k = t - c * K;
    float v = (c < 128) ? Wl[(size_t)k * 128 + c] : Wr[(size_t)k * 128 + (c - 128)];
    unsigned short hi = f2bf(v);
    unsigned short lo = f2bf(v - bf2f(hi));
    Wth[t] = hi; Wtl[t] = lo;
}

// --------------------------------------------------- MFMA split-bf16 dual GEMM v2
// B-fragments read DIRECTLY from global (W is 131 KB, L2-resident for all blocks).
// LDS holds only X, double-buffered, skewed (XR=36 shorts -> <=2-way banks).
// Block: 64 rows x 256 cols, 4 waves, wave-tile 64x64, 3 MFMA per frag pair.
template<int K>
__launch_bounds__(256)
__global__ void gemm_mfma(const unsigned short* __restrict__ Xh, const unsigned short* __restrict__ Xl,
                          const unsigned short* __restrict__ Wth, const unsigned short* __restrict__ Wtl,
                          const float* __restrict__ bl, const float* __restrict__ br,
                          float* __restrict__ Cl, float* __restrict__ Cr, int n)
{
    constexpr int KC = 32;
    constexpr int NCH = K / KC;
    constexpr int XR = 36;                       // short-stride skew
    __shared__ unsigned short XsH[2][64 * XR];   // 4.5 KB x2
    __shared__ unsigned short XsL[2][64 * XR];
    const int tid  = threadIdx.x;
    const int wave = tid >> 6;
    const int lane = tid & 63;
    const int quad = lane >> 4;
    const int l15  = lane & 15;
    const int row0 = blockIdx.x * 64;

    f32x4 acc[4][4];
    #pragma unroll
    for (int i = 0; i < 4; i++)
        #pragma unroll
        for (int j = 0; j < 4; j++) acc[i][j] = (f32x4){0.f, 0.f, 0.f, 0.f};

    // staging coords: thread -> (row sr, k-segment seg)
    const int sr  = tid >> 2, seg = tid & 3;
    const int srow = row0 + sr;

    // stage chunk 0
    {
        uint4 vh = make_uint4(0,0,0,0), vl = make_uint4(0,0,0,0);
        if (srow < n) {
            const size_t go = (size_t)srow * K + seg * 8;
            vh = *(const uint4*)(Xh + go);
            vl = *(const uint4*)(Xl + go);
        }
        *(uint4*)&XsH[0][sr * XR + seg * 8] = vh;
        *(uint4*)&XsL[0][sr * XR + seg * 8] = vl;
    }
    __syncthreads();

    for (int ch = 0; ch < NCH; ch++) {
        const int cur = ch & 1;
        const bool more = (ch + 1 < NCH);
        // prefetch next X chunk into registers (overlaps MFMA phase)
        uint4 nh = make_uint4(0,0,0,0), nl = make_uint4(0,0,0,0);
        if (more && srow < n) {
            const size_t go = (size_t)srow * K + (ch + 1) * KC + seg * 8;
            nh = *(const uint4*)(Xh + go);
            nl = *(const uint4*)(Xl + go);
        }
        // preload all B-fragments for this chunk from global (L2-hot)
        bf16x8 bh[4], bo[4];
        #pragma unroll
        for (int nt = 0; nt < 4; nt++) {
            const size_t wo = (size_t)(wave * 64 + nt * 16 + l15) * K + ch * KC + quad * 8;
            bh[nt] = *(const bf16x8*)(Wth + wo);
            bo[nt] = *(const bf16x8*)(Wtl + wo);
        }
        // A-fragments from LDS
        bf16x8 ah[4], al[4];
        #pragma unroll
        for (int mt = 0; mt < 4; mt++) {
            ah[mt] = *(const bf16x8*)&XsH[cur][(mt * 16 + l15) * XR + quad * 8];
            al[mt] = *(const bf16x8*)&XsL[cur][(mt * 16 + l15) * XR + quad * 8];
        }
        #pragma unroll
        for (int nt = 0; nt < 4; nt++) {
            #pragma unroll
            for (int mt = 0; mt < 4; mt++) {
                acc[mt][nt] = __builtin_amdgcn_mfma_f32_16x16x32_bf16(ah[mt], bh[nt], acc[mt][nt], 0, 0, 0);
                acc[mt][nt] = __builtin_amdgcn_mfma_f32_16x16x32_bf16(ah[mt], bo[nt], acc[mt][nt], 0, 0, 0);
                acc[mt][nt] = __builtin_amdgcn_mfma_f32_16x16x32_bf16(al[mt], bh[nt], acc[mt][nt], 0, 0, 0);
            }
        }
        if (more) {
            *(uint4*)&XsH[1 - cur][sr * XR + seg * 8] = nh;
            *(uint4*)&XsL[1 - cur][sr * XR + seg * 8] = nl;
        }
        __syncthreads();
    }

    // epilogue: C/D layout col=lane&15, row=quad*4+reg
    const bool isL = (wave < 2);
    const int colbase = (wave & 1) * 64;
    const float* bias = isL ? bl : br;
    float* C = isL ? Cl : Cr;
    #pragma unroll
    for (int nt = 0; nt < 4; nt++) {
        const float bv = bias[colbase + nt * 16 + l15];
        #pragma unroll
        for (int mt = 0; mt < 4; mt++) {
            #pragma unroll
            for (int r = 0; r < 4; r++) {
                const int row = row0 + mt * 16 + quad * 4 + r;
                if (row < n)
                    C[(size_t)row * 128 + colbase + nt * 16 + l15] = acc[mt][nt][r] + bv;
            }
        }
    }
}

// ---------------------------------------------------------------- CSR build
__global__ void deg_hist(const int* __restrict__ dst, int* __restrict__ deg) {
    int e = blockIdx.x * 256 + threadIdx.x;
    if (e < N_EDGES) atomicAdd(&deg[dst[e]], 1);
}

__launch_bounds__(SCAN_B)
__global__ void scan_block(const int* __restrict__ deg, int* __restrict__ rowptr,
                           int* __restrict__ btot)
{
    __shared__ int s[SCAN_B];
    const int tid = threadIdx.x;
    const int i = blockIdx.x * SCAN_B + tid;
    int v = (i < N_NODES) ? deg[i] : 0;
    s[tid] = v;
    __syncthreads();
    for (int off = 1; off < SCAN_B; off <<= 1) {
        int t = (tid >= off) ? s[tid - off] : 0;
        __syncthreads();
        s[tid] += t;
        __syncthreads();
    }
    if (i < N_NODES) rowptr[i] = s[tid] - v;
    if (tid == SCAN_B - 1) btot[blockIdx.x] = s[SCAN_B - 1];
}

__global__ void scan_btot(const int* __restrict__ btot, int* __restrict__ boff) {
    if (threadIdx.x == 0) {
        int a = 0;
        for (int b = 0; b < NB; b++) { boff[b] = a; a += btot[b]; }
        boff[NB] = a;
    }
}

__global__ void scan_add(const int* __restrict__ boff, int* __restrict__ rowptr,
                         int* __restrict__ cursor)
{
    int i = blockIdx.x * 256 + threadIdx.x;
    if (i < N_NODES) {
        int r = rowptr[i] + boff[i >> 10];
        rowptr[i] = r;
        cursor[i] = r;
    }
    if (i == N_NODES) rowptr[N_NODES] = boff[NB];
}

__global__ void scatter_csr(const int* __restrict__ src, const int* __restrict__ dst,
                            int* __restrict__ cursor, int* __restrict__ csr_src)
{
    int e = blockIdx.x * 256 + threadIdx.x;
    if (e >= N_EDGES) return;
    int pos = atomicAdd(&cursor[dst[e]], 1);
    csr_src[pos] = src[e];
}

// graph boundaries from sorted batch: gptr[G+1]
__global__ void build_gptr(const int* __restrict__ batch, int* __restrict__ gptr) {
    int i = blockIdx.x * 256 + threadIdx.x;
    if (i > N_NODES) return;
    if (i == 0) {
        for (int g = 0; g <= batch[0]; g++) gptr[g] = 0;
    } else if (i == N_NODES) {
        for (int g = batch[N_NODES - 1] + 1; g <= GG; g++) gptr[g] = N_NODES;
    } else {
        int b0 = batch[i - 1], b1 = batch[i];
        for (int g = b0 + 1; g <= b1; g++) gptr[g] = i;
    }
}

// ------------------------------------------------- fused per-node attention v2
// one wave per dst node, FOUR edges in flight (16 lanes x 8 dims each).
// leaky = max(t, 0.2t); ballot-gated rescale skips exp/rescale when max unchanged.
__launch_bounds__(256)
__global__ void node_attn(const float* __restrict__ xl, const float* __restrict__ xr,
                          const int* __restrict__ rowptr, const int* __restrict__ csr_src,
                          const float* __restrict__ att, const float* __restrict__ bvec,
                          unsigned short* __restrict__ Hh, unsigned short* __restrict__ Hl)
{
    const int node = (blockIdx.x * 256 + threadIdx.x) >> 6;
    const int lane = threadIdx.x & 63;
    if (node >= N_NODES) return;
    const int eslot = lane >> 4;         // edge slot 0..3
    const int li    = lane & 15;         // dims li*8 .. li*8+7 (head = li>>2)

    const float* xrp = xr + (size_t)node * HD + li * 8;
    const float4 xr0 = *(const float4*)(xrp);
    const float4 xr1 = *(const float4*)(xrp + 4);
    const float4 aw0 = *(const float4*)(att + li * 8);
    const float4 aw1 = *(const float4*)(att + li * 8 + 4);
    const int beg = rowptr[node];
    const int end = rowptr[node + 1];

    float m = -1e30f, l = 0.f;
    float4 a0 = make_float4(0.f, 0.f, 0.f, 0.f);
    float4 a1 = make_float4(0.f, 0.f, 0.f, 0.f);

    // prefetch first edge quad
    int e0 = beg + eslot;
    int s0 = (e0 < end) ? csr_src[e0] : 0;
    const float* rp0 = xl + (size_t)s0 * HD + li * 8;
    float4 v0 = *(const float4*)(rp0);
    float4 v1 = *(const float4*)(rp0 + 4);

    for (int base = beg; base < end; base += 4) {
        const bool valid = (base + eslot) < end;
        float4 n0 = v0, n1 = v1;
        if (base + 4 < end) {
            int e2 = base + 4 + eslot;
            int s2 = (e2 < end) ? csr_src[e2] : 0;
            const float* rp = xl + (size_t)s2 * HD + li * 8;
            n0 = *(const float4*)(rp);
            n1 = *(const float4*)(rp + 4);
        }
        // score partial over this lane's 8 dims: leaky = max(t, 0.2t)
        float t, p;
        t = v0.x + xr0.x; t = fmaxf(t, NEG_SLOPE * t); p  = t * aw0.x;
        t = v0.y + xr0.y; t = fmaxf(t, NEG_SLOPE * t); p += t * aw0.y;
        t = v0.z + xr0.z; t = fmaxf(t, NEG_SLOPE * t); p += t * aw0.z;
        t = v0.w + xr0.w; t = fmaxf(t, NEG_SLOPE * t); p += t * aw0.w;
        t = v1.x + xr1.x; t = fmaxf(t, NEG_SLOPE * t); p += t * aw1.x;
        t = v1.y + xr1.y; t = fmaxf(t, NEG_SLOPE * t); p += t * aw1.y;
        t = v1.z + xr1.z; t = fmaxf(t, NEG_SLOPE * t); p += t * aw1.z;
        t = v1.w + xr1.w; t = fmaxf(t, NEG_SLOPE * t); p += t * aw1.w;
        p += __shfl_xor(p, 1);
        p += __shfl_xor(p, 2);           // head score replicated in 4-lane group

        if (!__any(valid && (p > m))) {  // fast path: max unchanged anywhere
            const float w = valid ? __expf(p - m) : 0.f;
            l += w;
            a0.x += w * v0.x; a0.y += w * v0.y; a0.z += w * v0.z; a0.w += w * v0.w;
            a1.x += w * v1.x; a1.y += w * v1.y; a1.z += w * v1.z; a1.w += w * v1.w;
        } else {
            const float mn = valid ? fmaxf(m, p) : m;
            const float sc = __expf(m - mn);
            const float w  = valid ? __expf(p - mn) : 0.f;
            l = l * sc + w;
            a0.x = a0.x * sc + w * v0.x; a0.y = a0.y * sc + w * v0.y;
            a0.z = a0.z * sc + w * v0.z; a0.w = a0.w * sc + w * v0.w;
            a1.x = a1.x * sc + w * v1.x; a1.y = a1.y * sc + w * v1.y;
            a1.z = a1.z * sc + w * v1.z; a1.w = a1.w * sc + w * v1.w;
            m = mn;
        }
        v0 = n0; v1 = n1;
    }

    // merge the 4 edge-slot softmax states (xor 16, then xor 32)
    #pragma unroll
    for (int off = 16; off <= 32; off <<= 1) {
        const float mo = __shfl_xor(m, off);
        const float lo = __shfl_xor(l, off);
        float4 b0, b1;
        b0.x = __shfl_xor(a0.x, off); b0.y = __shfl_xor(a0.y, off);
        b0.z = __shfl_xor(a0.z, off); b0.w = __shfl_xor(a0.w, off);
        b1.x = __shfl_xor(a1.x, off); b1.y = __shfl_xor(a1.y, off);
        b1.z = __shfl_xor(a1.z, off); b1.w = __shfl_xor(a1.w, off);
        const float mm = fmaxf(m, mo);
        const float e1 = __expf(m - mm);
        const float e2 = __expf(mo - mm);
        l = l * e1 + lo * e2;
        a0.x = a0.x * e1 + b0.x * e2; a0.y = a0.y * e1 + b0.y * e2;
        a0.z = a0.z * e1 + b0.z * e2; a0.w = a0.w * e1 + b0.w * e2;
        a1.x = a1.x * e1 + b1.x * e2; a1.y = a1.y * e1 + b1.y * e2;
        a1.z = a1.z * e1 + b1.z * e2; a1.w = a1.w * e1 + b1.w * e2;
        m = mm;
    }

    if (eslot == 0) {
        const float inv = (l > 0.f) ? 1.f / l : 0.f;
        const float4 bb0 = *(const float4*)(bvec + li * 8);
        const float4 bb1 = *(const float4*)(bvec + li * 8 + 4);
        float o[8];
        o[0] = a0.x * inv + bb0.x; o[1] = a0.y * inv + bb0.y;
        o[2] = a0.z * inv + bb0.z; o[3] = a0.w * inv + bb0.w;
        o[4] = a1.x * inv + bb1.x; o[5] = a1.y * inv + bb1.y;
        o[6] = a1.z * inv + bb1.z; o[7] = a1.w * inv + bb1.w;
        uint4 ph, pl;
        unsigned* php = (unsigned*)&ph;
        unsigned* plp = (unsigned*)&pl;
        #pragma unroll
        for (int j = 0; j < 4; j++) {
            float u0 = o[2*j], u1 = o[2*j+1];
            u0 = (u0 > 0.f) ? u0 : expm1f(u0);
            u1 = (u1 > 0.f) ? u1 : expm1f(u1);
            unsigned short h0 = f2bf(u0), h1 = f2bf(u1);
            unsigned short q0 = f2bf(u0 - bf2f(h0)), q1 = f2bf(u1 - bf2f(h1));
            php[j] = (unsigned)h0 | ((unsigned)h1 << 16);
            plp[j] = (unsigned)q0 | ((unsigned)q1 << 16);
        }
        *(uint4*)(Hh + (size_t)node * HD + li * 8) = ph;
        *(uint4*)(Hl + (size_t)node * HD + li * 8) = pl;
    }
}

// ------------------------------------------ fused mean-pool + linear head
__launch_bounds__(256)
__global__ void pool_head(const unsigned short* __restrict__ Hh, const unsigned short* __restrict__ Hl,
                          const int* __restrict__ gptr, const float* __restrict__ Wh,
                          const float* __restrict__ bh, float* __restrict__ out)
{
    const int g = (blockIdx.x * 256 + threadIdx.x) >> 6;
    const int lane = threadIdx.x & 63;
    if (g >= GG) return;
    const int b0 = gptr[g], b1 = gptr[g + 1];
    const float2 w = *(const float2*)(Wh + lane * 2);
    float sx = 0.f, sy = 0.f;
    for (int i = b0; i < b1; i++) {
        const unsigned vh = *(const unsigned*)(Hh + (size_t)i * HD + lane * 2);
        const unsigned vl = *(const unsigned*)(Hl + (size_t)i * HD + lane * 2);
        sx += bf2f((unsigned short)(vh & 0xffff)) + bf2f((unsigned short)(vl & 0xffff));
        sy += bf2f((unsigned short)(vh >> 16))    + bf2f((unsigned short)(vl >> 16));
    }
    float d = sx * w.x + sy * w.y;
    d += __shfl_xor(d, 1);
    d += __shfl_xor(d, 2);
    d += __shfl_xor(d, 4);
    d += __shfl_xor(d, 8);
    d += __shfl_xor(d, 16);
    d += __shfl_xor(d, 32);
    if (lane == 0) out[g] = d / fmaxf((float)(b1 - b0), 1.f) + bh[0];
}

// ---------------------------------------------------------------- launch
extern "C" void kernel_launch(void* const* d_in, const int* in_sizes, int n_in,
                              void* d_out, int out_size, void* d_ws, size_t ws_size,
                              hipStream_t stream)
{
    const float* x     = (const float*)d_in[0];
    const int*   edge  = (const int*)d_in[1];
    const int*   batch = (const int*)d_in[2];
    const int*   src   = edge;
    const int*   dst   = edge + N_EDGES;
    const float* Wh    = (const float*)d_in[21];
    const float* bh    = (const float*)d_in[22];
    float* out = (float*)d_out;

    const size_t N128 = (size_t)N_NODES * HD;
    float* buf_xl = (float*)d_ws;                       // N*128 f32
    float* buf_xr = buf_xl + N128;                      // N*128 f32
    unsigned short* Xh  = (unsigned short*)(buf_xr + N128);   // N*128 bf16
    unsigned short* Xl_ = Xh + N128;                    // N*128 bf16
    unsigned short* Wth = Xl_ + N128;                   // 3 * 256*128 bf16
    unsigned short* Wtl = Wth + 3 * 256 * 128;          // 3 * 256*128 bf16
    int* deg     = (int*)(Wtl + 3 * 256 * 128);         // N
    int* rowptr  = deg + N_NODES;                       // N+1
    int* cursor  = rowptr + N_NODES + 1;                // N
    int* csr_src = cursor + N_NODES;                    // E
    int* btot    = csr_src + N_EDGES;                   // NB
    int* boff    = btot + NB;                           // NB+1
    int* gptr    = boff + NB + 1;                       // G+1

    // ---- CSR + graph-boundary build (layer-invariant)
    hipMemsetAsync(deg, 0, (size_t)N_NODES * sizeof(int), stream);
    deg_hist<<<(N_EDGES + 255) / 256, 256, 0, stream>>>(dst, deg);
    scan_block<<<NB, SCAN_B, 0, stream>>>(deg, rowptr, btot);
    scan_btot<<<1, 64, 0, stream>>>(btot, boff);
    scan_add<<<(N_NODES + 256) / 256, 256, 0, stream>>>(boff, rowptr, cursor);
    scatter_csr<<<(N_EDGES + 255) / 256, 256, 0, stream>>>(src, dst, cursor, csr_src);
    build_gptr<<<(N_NODES + 256) / 256, 256, 0, stream>>>(batch, gptr);

    // ---- weight + input split-bf16 conversion
    convert_x<<<(N_NODES * 64 + 255) / 256, 256, 0, stream>>>(x, Xh, Xl_, N_NODES * 64);
    for (int l = 0; l < 3; l++) {
        const int K = (l == 0) ? 64 : 128;
        convert_w<<<(256 * K + 255) / 256, 256, 0, stream>>>(
            (const float*)d_in[3 + 6 * l], (const float*)d_in[5 + 6 * l],
            Wth + l * 256 * 128, Wtl + l * 256 * 128, K);
    }

    const int gemm_grid = (N_NODES + 63) / 64;
    const int attn_grid = (N_NODES + 3) / 4;

    for (int l = 0; l < 3; l++) {
        const float* bl  = (const float*)d_in[4 + 6 * l];
        const float* br  = (const float*)d_in[6 + 6 * l];
        const float* att = (const float*)d_in[7 + 6 * l];
        const float* bb  = (const float*)d_in[8 + 6 * l];

        if (l == 0)
            gemm_mfma<64><<<gemm_grid, 256, 0, stream>>>(Xh, Xl_, Wth, Wtl,
                                                         bl, br, buf_xl, buf_xr, N_NODES);
        else
            gemm_mfma<128><<<gemm_grid, 256, 0, stream>>>(Xh, Xl_,
                                                          Wth + l * 256 * 128, Wtl + l * 256 * 128,
                                                          bl, br, buf_xl, buf_xr, N_NODES);
        node_attn<<<attn_grid, 256, 0, stream>>>(buf_xl, buf_xr, rowptr, csr_src,
                                                 att, bb, Xh, Xl_);
    }

    pool_head<<<GG / 4, 256, 0, stream>>>(Xh, Xl_, gptr, Wh, bh, out);
}